// Round 25
// baseline (89.396 us; speedup 1.0000x reference)
//
#include <hip/hip_runtime.h>
#include <stdint.h>

// N=2048, M=128, D_IN=352, H1=512, D=256, OUT_C=13.  All device tensors FLOAT32.
// Round 25: launch-count round.  proj fused into enc2 epilogue (split-K over c,
// atomicAdd into memset-zeroed PA2/PB2; by==0 block adds the bn1 affine const);
// mw2b/mw3b cvt moved to enc1 spare blocks; s_setprio(1) around main_attn phase2
// MFMA (T5 independent-wave case).  4 launches -> 3 (+1 memset).
// main_attn otherwise frozen at R17 (52.4us).

typedef __attribute__((ext_vector_type(4))) float float4_t;
typedef __attribute__((ext_vector_type(4))) float f32x4;
typedef __attribute__((ext_vector_type(8))) short bf16x8;
typedef __attribute__((ext_vector_type(8))) unsigned short ushort8_t;
typedef __attribute__((ext_vector_type(4))) unsigned short ushort4_t;
typedef unsigned short ushort_t;

__device__ __forceinline__ float b2f(unsigned short u) {
  union { unsigned int i; float f; } v; v.i = ((unsigned int)u) << 16; return v.f;
}
__device__ __forceinline__ unsigned short f2b(float f) {
  union { float f; unsigned int i; } v; v.f = f;
  unsigned int x = v.i;
  return (unsigned short)((x + 0x7FFFu + ((x >> 16) & 1u)) >> 16);
}

template<int ISBF>
__device__ __forceinline__ ushort8_t ld8(const void* base, size_t idx) {
  if constexpr (ISBF) {
    return *(const ushort8_t*)((const ushort_t*)base + idx);
  } else {
    const float* p = (const float*)base + idx;
    float4_t v0 = *(const float4_t*)p;
    float4_t v1 = *(const float4_t*)(p + 4);
    ushort8_t u;
    #pragma unroll
    for (int e = 0; e < 4; ++e) { u[e] = f2b(v0[e]); u[4 + e] = f2b(v1[e]); }
    return u;
  }
}

// ---------- MFMA encoder: 32x32 tile, K_STEP=64 dbuf ----------
// DO_CVT (enc1): bx>=68 & by==0 blocks convert mw2/mw3 -> bf16.
// DO_PROJ (enc2): epilogue stages the activation tile in LDS and atomically
// accumulates the mw1-projection into PA2 (A, +bias const at by==0) / PB2 (B).
template<int XBF, int WBF, int OUT_BF16, int DO_CVT, int DO_PROJ>
__global__ __launch_bounds__(256) void enc_mfma(
    const void* __restrict__ XA, const void* __restrict__ WA,
    const float* __restrict__ bA, const float* __restrict__ gA, const float* __restrict__ beA,
    void* __restrict__ YA,
    const void* __restrict__ XB, const void* __restrict__ WB,
    const float* __restrict__ bB, const float* __restrict__ gB, const float* __restrict__ beB,
    void* __restrict__ YB, ushort_t* __restrict__ YBTb,
    int J, int K, int nbxA,
    const float* __restrict__ mw2, const float* __restrict__ mw3,
    ushort_t* __restrict__ mw2b, ushort_t* __restrict__ mw3b,
    const float* __restrict__ mw1, const float* __restrict__ mg1,
    const float* __restrict__ mb1, const float* __restrict__ mbe1,
    float* __restrict__ PA2, float* __restrict__ PB2)
{
  __shared__ ushort_t Xs[2][32][72];
  __shared__ ushort_t Ws[2][32][72];
  __shared__ float tileT[32][33];
  const int bx = blockIdx.x, by = blockIdx.y;

  if constexpr (DO_CVT) {
    if (bx >= nbxA + 4) {               // cvt blocks (enc1 grid x = 77)
      if (by != 0) return;
      const int g = (bx - nbxA - 4) * 256 + threadIdx.x;   // 2304 groups of 8
      const float* s; ushort_t* d; int j;
      if (g < 256) { s = mw2; d = mw2b; j = g; }
      else         { s = mw3; d = mw3b; j = g - 256; }
      float4_t v0 = *(const float4_t*)&s[(size_t)j * 8];
      float4_t v1 = *(const float4_t*)&s[(size_t)j * 8 + 4];
      ushort8_t u;
      #pragma unroll
      for (int e = 0; e < 4; ++e) { u[e] = f2b(v0[e]); u[4 + e] = f2b(v1[e]); }
      *(ushort8_t*)&d[(size_t)j * 8] = u;
      return;
    }
  }

  const void* X; const void* W;
  const float *bb, *gg, *bev; void* Y; int i0, isB;
  if (bx < nbxA) { X = XA; W = WA; bb = bA; gg = gA; bev = beA; Y = YA; i0 = bx * 32; isB = 0; }
  else           { X = XB; W = WB; bb = bB; gg = gB; bev = beB; Y = YB; i0 = (bx - nbxA) * 32; isB = 1; }
  const int j0 = by * 32;
  const int tid = threadIdx.x, w = tid >> 6, lane = tid & 63, lg = lane >> 4, lr = lane & 15;
  const int mt = w >> 1, ct = w & 1;
  const int row = tid >> 3, k8 = (tid & 7) * 8;   // 32 rows x 8 chunks

  f32x4 acc = f32x4{0.f, 0.f, 0.f, 0.f};

  ushort8_t xv = ld8<XBF>(X, (size_t)(i0 + row) * K + k8);
  ushort8_t wv = ld8<WBF>(W, (size_t)(j0 + row) * K + k8);
  for (int kt = 0; kt < K; kt += 64) {
    const int buf = (kt >> 6) & 1;
    *(ushort8_t*)&Xs[buf][row][k8] = xv;
    *(ushort8_t*)&Ws[buf][row][k8] = wv;
    __syncthreads();
    if (kt + 64 < K && kt + 64 + k8 < K) {
      xv = ld8<XBF>(X, (size_t)(i0 + row) * K + kt + 64 + k8);
      wv = ld8<WBF>(W, (size_t)(j0 + row) * K + kt + 64 + k8);
    }
    bf16x8 af0 = *(const bf16x8*)&Xs[buf][mt * 16 + lr][lg * 8];
    bf16x8 bf0 = *(const bf16x8*)&Ws[buf][ct * 16 + lr][lg * 8];
    acc = __builtin_amdgcn_mfma_f32_16x16x32_bf16(af0, bf0, acc, 0, 0, 0);
    if (kt + 32 < K) {
      bf16x8 af1 = *(const bf16x8*)&Xs[buf][mt * 16 + lr][32 + lg * 8];
      bf16x8 bf1 = *(const bf16x8*)&Ws[buf][ct * 16 + lr][32 + lg * 8];
      acc = __builtin_amdgcn_mfma_f32_16x16x32_bf16(af1, bf1, acc, 0, 0, 0);
    }
  }
  const int c = j0 + ct * 16 + lr;
  const float g = gg[c], bv = bb[c], ev = bev[c];
  float tv[4];
  #pragma unroll
  for (int r = 0; r < 4; ++r) {
    const int rowo = i0 + mt * 16 + 4 * lg + r;
    tv[r] = fmaxf(g * (acc[r] + bv) + ev, 0.f);
    if (OUT_BF16) ((ushort_t*)Y)[(size_t)rowo * J + c] = f2b(tv[r]);
    else {
      ((float*)Y)[(size_t)rowo * J + c] = tv[r];
      if (isB && YBTb) YBTb[(size_t)c * 128 + rowo] = f2b(tv[r]);
    }
  }

  if constexpr (DO_PROJ) {
    // stage activation tile: tileT[row_local][c_local]
    #pragma unroll
    for (int r = 0; r < 4; ++r)
      tileT[mt * 16 + 4 * lg + r][ct * 16 + lr] = tv[r];
    __syncthreads();
    // split-K proj: thread -> (row_local = tid>>3, 4 k starting at (tid&7)*4)
    const int rowl = tid >> 3, k0 = (tid & 7) * 4;
    float s0 = 0.f, s1 = 0.f, s2 = 0.f, s3 = 0.f;
    #pragma unroll 4
    for (int cl = 0; cl < 32; cl += 4) {
      float4_t av = *(const float4_t*)&tileT[rowl][cl];
      float4_t w0 = *(const float4_t*)&mw1[(size_t)(k0 + 0) * 256 + j0 + cl];
      float4_t w1 = *(const float4_t*)&mw1[(size_t)(k0 + 1) * 256 + j0 + cl];
      float4_t w2 = *(const float4_t*)&mw1[(size_t)(k0 + 2) * 256 + j0 + cl];
      float4_t w3 = *(const float4_t*)&mw1[(size_t)(k0 + 3) * 256 + j0 + cl];
      #pragma unroll
      for (int e = 0; e < 4; ++e) {
        s0 = fmaf(av[e], w0[e], s0);
        s1 = fmaf(av[e], w1[e], s1);
        s2 = fmaf(av[e], w2[e], s2);
        s3 = fmaf(av[e], w3[e], s3);
      }
    }
    const int rowg = i0 + rowl;
    float* P = isB ? PB2 : PA2;
    float sv[4] = { s0, s1, s2, s3 };
    #pragma unroll
    for (int kk = 0; kk < 4; ++kk) {
      const int k = k0 + kk;
      float v = mg1[k] * sv[kk];
      if (!isB && by == 0) v += mg1[k] * mb1[k] + mbe1[k];   // bias const once
      atomicAdd(&P[(size_t)rowg * 32 + k], v);
    }
  }
}

// ---------- fused main kernel (R17 frozen + setprio around phase2 MFMA) ----------
// MFMA 16x16x32_bf16: A frag m=lane&15,k=(lane>>4)*8+e; B frag c=lane&15,same k;
// C/D col=lane&15,row=(lane>>4)*4+reg.
// Per-wave slab: h2[128][72] bf16 + att[256] f32 = 19456B; 4 waves/block = 77824B.
__global__ __launch_bounds__(256, 2) void main_attn(
    const float* __restrict__ PA2, const float* __restrict__ PB2,
    const float* __restrict__ A, const ushort_t* __restrict__ BmTb,
    const ushort_t* __restrict__ mw2b, const float* __restrict__ mb2,
    const float* __restrict__ mg2, const float* __restrict__ mbe2,
    const ushort_t* __restrict__ mw3b, const float* __restrict__ mb3,
    const float* __restrict__ mg3, const float* __restrict__ mbe3,
    const float* __restrict__ fcw, const float* __restrict__ fcb,
    float* __restrict__ outp)
{
  __shared__ __align__(16) char smem[77824];
  const int tid = threadIdx.x;
  const int w = tid >> 6, lane = tid & 63, lg = lane >> 4, lr = lane & 15;
  const int n = blockIdx.x * 4 + w;
  ushort_t* h2s = (ushort_t*)(smem + w * 19456);
  float* attL   = (float*)(smem + w * 19456 + 18432);
  const float LOG2E = 1.4426950408889634f;

  // ---- phase1 ----
  {
    bf16x8 b1[4];
    float g2h[4], b2h[4], e2h[4];
    #pragma unroll
    for (int jt = 0; jt < 4; ++jt) {
      b1[jt] = *(const bf16x8*)&mw2b[(jt * 16 + lr) * 32 + lg * 8];
      const int j = jt * 16 + lr;
      g2h[jt] = mg2[j]; b2h[jt] = mb2[j]; e2h[jt] = mbe2[j];
    }
    const float* pa = &PA2[(size_t)n * 32 + lg * 8];
    float4_t pa0 = *(const float4_t*)pa;
    float4_t pa1 = *(const float4_t*)(pa + 4);
    #pragma unroll
    for (int mt = 0; mt < 8; ++mt) {
      const float* pb = &PB2[(size_t)(mt * 16 + lr) * 32 + lg * 8];
      float4_t pb0 = *(const float4_t*)pb;
      float4_t pb1 = *(const float4_t*)(pb + 4);
      bf16x8 a1;
      #pragma unroll
      for (int e = 0; e < 4; ++e) {
        a1[e]     = (short)f2b(fmaxf(pa0[e] - pb0[e], 0.f));
        a1[4 + e] = (short)f2b(fmaxf(pa1[e] - pb1[e], 0.f));
      }
      f32x4 acc1[4];
      #pragma unroll
      for (int jt = 0; jt < 4; ++jt) acc1[jt] = f32x4{0.f, 0.f, 0.f, 0.f};
      #pragma unroll
      for (int jt = 0; jt < 4; ++jt)
        acc1[jt] = __builtin_amdgcn_mfma_f32_16x16x32_bf16(a1, b1[jt], acc1[jt], 0, 0, 0);
      #pragma unroll
      for (int jt = 0; jt < 4; ++jt)
        #pragma unroll
        for (int r = 0; r < 4; ++r)
          h2s[(mt * 16 + 4 * lg + r) * 72 + jt * 16 + lr] =
              f2b(fmaxf(g2h[jt] * (acc1[jt][r] + b2h[jt]) + e2h[jt], 0.f));
    }
  }
  // intra-wave ordering: compiler lgkmcnt; no barrier.

  // ---- load ALL phase2 A-frags once ----
  bf16x8 af0[8], af1[8];
  #pragma unroll
  for (int mt = 0; mt < 8; ++mt) {
    af0[mt] = *(const bf16x8*)&h2s[(mt * 16 + lr) * 72 + lg * 8];
    af1[mt] = *(const bf16x8*)&h2s[(mt * 16 + lr) * 72 + 32 + lg * 8];
  }

  // ---- phase2 + softmax: 16 ct-iterations, MFMA from registers ----
  #pragma unroll 4
  for (int ct = 0; ct < 16; ++ct) {
    const int c = ct * 16 + lr;
    bf16x8 bfr0 = *(const bf16x8*)&mw3b[(size_t)c * 64 + lg * 8];
    bf16x8 bfr1 = *(const bf16x8*)&mw3b[(size_t)c * 64 + 32 + lg * 8];
    f32x4 acc[8];
    #pragma unroll
    for (int mt = 0; mt < 8; ++mt) acc[mt] = f32x4{0.f, 0.f, 0.f, 0.f};
    __builtin_amdgcn_s_setprio(1);
    #pragma unroll
    for (int mt = 0; mt < 8; ++mt) {
      acc[mt] = __builtin_amdgcn_mfma_f32_16x16x32_bf16(af0[mt], bfr0, acc[mt], 0, 0, 0);
      acc[mt] = __builtin_amdgcn_mfma_f32_16x16x32_bf16(af1[mt], bfr1, acc[mt], 0, 0, 0);
    }
    __builtin_amdgcn_s_setprio(0);
    const float g = mg3[c];
    const float gs = g * LOG2E;
    const float cs = (g * mb3[c] + mbe3[c]) * LOG2E;
    f32x4 sm4 = f32x4{0.f, 0.f, 0.f, 0.f};
    f32x4 wb4 = f32x4{0.f, 0.f, 0.f, 0.f};
    #pragma unroll
    for (int mt = 0; mt < 8; ++mt) {
      ushort4_t bv4 = *(const ushort4_t*)&BmTb[(size_t)c * 128 + mt * 16 + 4 * lg];
      #pragma unroll
      for (int r = 0; r < 4; ++r) {
        float t = fmaf(gs, acc[mt][r], cs);
        float p = __builtin_amdgcn_exp2f(__builtin_amdgcn_fmed3f(t, 0.f, 80.f));
        sm4[r] += p;
        wb4[r] = fmaf(p, b2f(bv4[r]), wb4[r]);
      }
    }
    float sm = (sm4[0] + sm4[1]) + (sm4[2] + sm4[3]);
    float wb = (wb4[0] + wb4[1]) + (wb4[2] + wb4[3]);
    sm += __shfl_xor(sm, 16, 64);  wb += __shfl_xor(wb, 16, 64);
    sm += __shfl_xor(sm, 32, 64);  wb += __shfl_xor(wb, 32, 64);
    if (lg == 0)
      attL[c] = A[(size_t)n * 256 + c] - wb / sm;
  }

  // ---- fc (intra-wave): lane covers c = lane*4..lane*4+3 ----
  {
    float4_t av = *(const float4_t*)&attL[lane * 4];
    #pragma unroll
    for (int o = 0; o < 13; ++o) {
      float4_t wv = *(const float4_t*)&fcw[(size_t)o * 256 + lane * 4];
      float s = av[0] * wv[0];
      s = fmaf(av[1], wv[1], s);
      s = fmaf(av[2], wv[2], s);
      s = fmaf(av[3], wv[3], s);
      #pragma unroll
      for (int st = 1; st <= 32; st <<= 1) s += __shfl_xor(s, st, 64);
      if (lane == 0) outp[(size_t)n * 13 + o] = s + fcb[o];
    }
  }
}

extern "C" void kernel_launch(void* const* d_in, const int* in_sizes, int n_in,
                              void* d_out, int out_size, void* d_ws, size_t ws_size,
                              hipStream_t stream)
{
  const float* ext = (const float*)d_in[0];
  const float* lab = (const float*)d_in[1];
  const float* w1a = (const float*)d_in[2];
  const float* b1a = (const float*)d_in[3];
  const float* g1a = (const float*)d_in[4];
  const float* be1a= (const float*)d_in[5];
  const float* w1b = (const float*)d_in[6];
  const float* b1b = (const float*)d_in[7];
  const float* g1b = (const float*)d_in[8];
  const float* be1b= (const float*)d_in[9];
  const float* w2a = (const float*)d_in[10];
  const float* b2a = (const float*)d_in[11];
  const float* g2a = (const float*)d_in[12];
  const float* be2a= (const float*)d_in[13];
  const float* w2b = (const float*)d_in[14];
  const float* b2b = (const float*)d_in[15];
  const float* g2b = (const float*)d_in[16];
  const float* be2b= (const float*)d_in[17];
  const float* mw1 = (const float*)d_in[18];
  const float* mb1 = (const float*)d_in[19];
  const float* mg1 = (const float*)d_in[20];
  const float* mbe1= (const float*)d_in[21];
  const float* mw2 = (const float*)d_in[22];
  const float* mb2 = (const float*)d_in[23];
  const float* mg2 = (const float*)d_in[24];
  const float* mbe2= (const float*)d_in[25];
  const float* mw3 = (const float*)d_in[26];
  const float* mb3 = (const float*)d_in[27];
  const float* mg3 = (const float*)d_in[28];
  const float* mbe3= (const float*)d_in[29];
  const float* fcw = (const float*)d_in[30];
  const float* fcb = (const float*)d_in[31];

  char* ws = (char*)d_ws;
  ushort_t* Y1ab = (ushort_t*)(ws);                       // [0,2M) bf16 (dead after enc2)
  float*    Aenc = (float*)(ws + (2u << 20));             // [2M,4M)
  char* b5 = ws + (4u << 20);
  ushort_t* mw2b  = (ushort_t*)(b5);                      // 64x32 bf16
  ushort_t* mw3b  = (ushort_t*)(b5 + 4096);               // 256x64 bf16
  ushort_t* Y1bb  = (ushort_t*)(b5 + 36864);              // 128x512 bf16
  float*    Benc  = (float*)(b5 + 167936);                // 128x256 f32 (dead; kept as Y)
  ushort_t* BencTb= (ushort_t*)(b5 + 299008);             // 256x128 bf16 (64KB)
  float*    PA2   = (float*)(b5 + 364544);                // 2048x32 f32 (256KB)
  float*    PB2   = (float*)(b5 + 626688);                // 128x32 f32 (16KB)

  hipMemsetAsync((void*)PA2, 0, 262144 + 16384, stream);
  enc_mfma<0, 0, 1, 1, 0><<<dim3(77, 16), 256, 0, stream>>>(
      (const void*)ext, (const void*)w1a, b1a, g1a, be1a, (void*)Y1ab,
      (const void*)lab, (const void*)w2a, b2a, g2a, be2a, (void*)Y1bb,
      (ushort_t*)nullptr, 512, 352, 64,
      mw2, mw3, mw2b, mw3b,
      (const float*)nullptr, (const float*)nullptr,
      (const float*)nullptr, (const float*)nullptr,
      (float*)nullptr, (float*)nullptr);
  enc_mfma<1, 0, 0, 0, 1><<<dim3(68, 8), 256, 0, stream>>>(
      (const void*)Y1ab, (const void*)w1b, b1b, g1b, be1b, (void*)Aenc,
      (const void*)Y1bb, (const void*)w2b, b2b, g2b, be2b, (void*)Benc,
      BencTb, 256, 512, 64,
      (const float*)nullptr, (const float*)nullptr,
      (ushort_t*)nullptr, (ushort_t*)nullptr,
      mw1, mg1, mb1, mbe1, PA2, PB2);
  main_attn<<<512, 256, 0, stream>>>(PA2, PB2, Aenc, BencTb,
                                     mw2b, mb2, mg2, mbe2, mw3b, mb3, mg3, mbe3,
                                     fcw, fcb, (float*)d_out);
}

// Round 26
// 82.384 us; speedup vs baseline: 1.0851x; 1.0851x over previous
//
#include <hip/hip_runtime.h>
#include <stdint.h>

// N=2048, M=128, D_IN=352, H1=512, D=256, OUT_C=13.  All device tensors FLOAT32.
// Round 26: REVERT to R24 (best: 82.56us).  R25's three changes (proj fusion w/
// atomics, setprio, cvt-in-enc1) were net-negative (89.4us) -> dropped.
// Config: main_attn = R17 structure (one wave per n, zero barriers, A-frags
// resident, no-max exp2 softmax); encoders = 32x32 tile K_STEP=64 dbuf;
// standalone proj with cvt tail.  absmax 0.0078 (4x margin).

typedef __attribute__((ext_vector_type(4))) float float4_t;
typedef __attribute__((ext_vector_type(4))) float f32x4;
typedef __attribute__((ext_vector_type(8))) short bf16x8;
typedef __attribute__((ext_vector_type(8))) unsigned short ushort8_t;
typedef __attribute__((ext_vector_type(4))) unsigned short ushort4_t;
typedef unsigned short ushort_t;

__device__ __forceinline__ float b2f(unsigned short u) {
  union { unsigned int i; float f; } v; v.i = ((unsigned int)u) << 16; return v.f;
}
__device__ __forceinline__ unsigned short f2b(float f) {
  union { float f; unsigned int i; } v; v.f = f;
  unsigned int x = v.i;
  return (unsigned short)((x + 0x7FFFu + ((x >> 16) & 1u)) >> 16);
}

template<int ISBF>
__device__ __forceinline__ ushort8_t ld8(const void* base, size_t idx) {
  if constexpr (ISBF) {
    return *(const ushort8_t*)((const ushort_t*)base + idx);
  } else {
    const float* p = (const float*)base + idx;
    float4_t v0 = *(const float4_t*)p;
    float4_t v1 = *(const float4_t*)(p + 4);
    ushort8_t u;
    #pragma unroll
    for (int e = 0; e < 4; ++e) { u[e] = f2b(v0[e]); u[4 + e] = f2b(v1[e]); }
    return u;
  }
}

// ---------- MFMA encoder: 32x32 tile, K_STEP=64 dbuf (2 MFMA/wave/barrier) ----------
template<int XBF, int WBF, int OUT_BF16>
__global__ __launch_bounds__(256) void enc_mfma(
    const void* __restrict__ XA, const void* __restrict__ WA,
    const float* __restrict__ bA, const float* __restrict__ gA, const float* __restrict__ beA,
    void* __restrict__ YA,
    const void* __restrict__ XB, const void* __restrict__ WB,
    const float* __restrict__ bB, const float* __restrict__ gB, const float* __restrict__ beB,
    void* __restrict__ YB, ushort_t* __restrict__ YBTb,
    int J, int K, int nbxA)
{
  __shared__ ushort_t Xs[2][32][72];
  __shared__ ushort_t Ws[2][32][72];
  const int bx = blockIdx.x, by = blockIdx.y;
  const void* X; const void* W;
  const float *bb, *gg, *bev; void* Y; int i0, isB;
  if (bx < nbxA) { X = XA; W = WA; bb = bA; gg = gA; bev = beA; Y = YA; i0 = bx * 32; isB = 0; }
  else           { X = XB; W = WB; bb = bB; gg = gB; bev = beB; Y = YB; i0 = (bx - nbxA) * 32; isB = 1; }
  const int j0 = by * 32;
  const int tid = threadIdx.x, w = tid >> 6, lane = tid & 63, lg = lane >> 4, lr = lane & 15;
  const int mt = w >> 1, ct = w & 1;
  const int row = tid >> 3, k8 = (tid & 7) * 8;   // 32 rows x 8 chunks

  f32x4 acc = f32x4{0.f, 0.f, 0.f, 0.f};

  ushort8_t xv = ld8<XBF>(X, (size_t)(i0 + row) * K + k8);
  ushort8_t wv = ld8<WBF>(W, (size_t)(j0 + row) * K + k8);
  for (int kt = 0; kt < K; kt += 64) {
    const int buf = (kt >> 6) & 1;
    *(ushort8_t*)&Xs[buf][row][k8] = xv;
    *(ushort8_t*)&Ws[buf][row][k8] = wv;
    __syncthreads();
    if (kt + 64 < K && kt + 64 + k8 < K) {
      xv = ld8<XBF>(X, (size_t)(i0 + row) * K + kt + 64 + k8);
      wv = ld8<WBF>(W, (size_t)(j0 + row) * K + kt + 64 + k8);
    }
    bf16x8 af0 = *(const bf16x8*)&Xs[buf][mt * 16 + lr][lg * 8];
    bf16x8 bf0 = *(const bf16x8*)&Ws[buf][ct * 16 + lr][lg * 8];
    acc = __builtin_amdgcn_mfma_f32_16x16x32_bf16(af0, bf0, acc, 0, 0, 0);
    if (kt + 32 < K) {
      bf16x8 af1 = *(const bf16x8*)&Xs[buf][mt * 16 + lr][32 + lg * 8];
      bf16x8 bf1 = *(const bf16x8*)&Ws[buf][ct * 16 + lr][32 + lg * 8];
      acc = __builtin_amdgcn_mfma_f32_16x16x32_bf16(af1, bf1, acc, 0, 0, 0);
    }
  }
  const int c = j0 + ct * 16 + lr;
  const float g = gg[c], bv = bb[c], ev = bev[c];
  #pragma unroll
  for (int r = 0; r < 4; ++r) {
    const int rowo = i0 + mt * 16 + 4 * lg + r;
    float t = fmaxf(g * (acc[r] + bv) + ev, 0.f);
    if (OUT_BF16) ((ushort_t*)Y)[(size_t)rowo * J + c] = f2b(t);
    else {
      ((float*)Y)[(size_t)rowo * J + c] = t;
      if (isB && YBTb) YBTb[(size_t)c * 128 + rowo] = f2b(t);
    }
  }
}

// ---------- proj: P = fold(X @ mw1^T); 4 rows/block, split-K-2; + cvt tail ----------
__global__ __launch_bounds__(256) void proj32(
    const float* __restrict__ Aenc, const float* __restrict__ Benc,
    const float* __restrict__ mw1, const float* __restrict__ mb1,
    const float* __restrict__ mg1, const float* __restrict__ mbe1,
    float* __restrict__ PA2, float* __restrict__ PB2, int nbxA,
    const float* __restrict__ mw2, const float* __restrict__ mw3,
    ushort_t* __restrict__ mw2b, ushort_t* __restrict__ mw3b)
{
  __shared__ float ps[4][32];
  const int tid = threadIdx.x, bx = blockIdx.x;
  if (bx >= nbxA + 32) {
    const int g = (bx - nbxA - 32) * 256 + tid;
    const float* s; ushort_t* d; int j;
    if (g < 256) { s = mw2; d = mw2b; j = g; }
    else         { s = mw3; d = mw3b; j = g - 256; }
    float4_t v0 = *(const float4_t*)&s[(size_t)j * 8];
    float4_t v1 = *(const float4_t*)&s[(size_t)j * 8 + 4];
    ushort8_t u;
    #pragma unroll
    for (int e = 0; e < 4; ++e) { u[e] = f2b(v0[e]); u[4 + e] = f2b(v1[e]); }
    *(ushort8_t*)&d[(size_t)j * 8] = u;
    return;
  }
  const float* X; float* P; int n0, wb;
  if (bx < nbxA) { X = Aenc; P = PA2; n0 = bx * 4; wb = 1; }
  else           { X = Benc; P = PB2; n0 = (bx - nbxA) * 4; wb = 0; }
  const int k = tid & 31, r = (tid >> 5) & 3, half = tid >> 7;
  const int n = n0 + r;
  const float* xp = &X[(size_t)n * 256 + half * 128];
  const float* wp = &mw1[k * 256 + half * 128];
  float s = 0.f;
  #pragma unroll 8
  for (int q = 0; q < 128; q += 4) {
    float4_t xv = *(const float4_t*)&xp[q];
    float4_t wv = *(const float4_t*)&wp[q];
    #pragma unroll
    for (int e = 0; e < 4; ++e) s = fmaf(xv[e], wv[e], s);
  }
  if (half == 1) ps[r][k] = s;
  __syncthreads();
  if (half == 0) {
    s += ps[r][k];
    P[(size_t)n * 32 + k] = wb ? (mg1[k] * (s + mb1[k]) + mbe1[k]) : (mg1[k] * s);
  }
}

// ---------- fused main kernel (R17 FROZEN): one wave = one n, zero barriers ----------
// MFMA 16x16x32_bf16: A frag m=lane&15,k=(lane>>4)*8+e; B frag c=lane&15,same k;
// C/D col=lane&15,row=(lane>>4)*4+reg.
// Per-wave slab: h2[128][72] bf16 + att[256] f32 = 19456B; 4 waves/block = 77824B.
__global__ __launch_bounds__(256, 2) void main_attn(
    const float* __restrict__ PA2, const float* __restrict__ PB2,
    const float* __restrict__ A, const ushort_t* __restrict__ BmTb,
    const ushort_t* __restrict__ mw2b, const float* __restrict__ mb2,
    const float* __restrict__ mg2, const float* __restrict__ mbe2,
    const ushort_t* __restrict__ mw3b, const float* __restrict__ mb3,
    const float* __restrict__ mg3, const float* __restrict__ mbe3,
    const float* __restrict__ fcw, const float* __restrict__ fcb,
    float* __restrict__ outp)
{
  __shared__ __align__(16) char smem[77824];
  const int tid = threadIdx.x;
  const int w = tid >> 6, lane = tid & 63, lg = lane >> 4, lr = lane & 15;
  const int n = blockIdx.x * 4 + w;
  ushort_t* h2s = (ushort_t*)(smem + w * 19456);
  float* attL   = (float*)(smem + w * 19456 + 18432);
  const float LOG2E = 1.4426950408889634f;

  // ---- phase1: h2[m][j] = relu(g2*(relu(PA2[n]-PB2[m]) @ mw2^T + b2) + be2) ----
  {
    bf16x8 b1[4];
    float g2h[4], b2h[4], e2h[4];
    #pragma unroll
    for (int jt = 0; jt < 4; ++jt) {
      b1[jt] = *(const bf16x8*)&mw2b[(jt * 16 + lr) * 32 + lg * 8];
      const int j = jt * 16 + lr;
      g2h[jt] = mg2[j]; b2h[jt] = mb2[j]; e2h[jt] = mbe2[j];
    }
    const float* pa = &PA2[(size_t)n * 32 + lg * 8];
    float4_t pa0 = *(const float4_t*)pa;
    float4_t pa1 = *(const float4_t*)(pa + 4);
    #pragma unroll
    for (int mt = 0; mt < 8; ++mt) {
      const float* pb = &PB2[(size_t)(mt * 16 + lr) * 32 + lg * 8];
      float4_t pb0 = *(const float4_t*)pb;
      float4_t pb1 = *(const float4_t*)(pb + 4);
      bf16x8 a1;
      #pragma unroll
      for (int e = 0; e < 4; ++e) {
        a1[e]     = (short)f2b(fmaxf(pa0[e] - pb0[e], 0.f));
        a1[4 + e] = (short)f2b(fmaxf(pa1[e] - pb1[e], 0.f));
      }
      f32x4 acc1[4];
      #pragma unroll
      for (int jt = 0; jt < 4; ++jt) acc1[jt] = f32x4{0.f, 0.f, 0.f, 0.f};
      #pragma unroll
      for (int jt = 0; jt < 4; ++jt)
        acc1[jt] = __builtin_amdgcn_mfma_f32_16x16x32_bf16(a1, b1[jt], acc1[jt], 0, 0, 0);
      #pragma unroll
      for (int jt = 0; jt < 4; ++jt)
        #pragma unroll
        for (int r = 0; r < 4; ++r)
          h2s[(mt * 16 + 4 * lg + r) * 72 + jt * 16 + lr] =
              f2b(fmaxf(g2h[jt] * (acc1[jt][r] + b2h[jt]) + e2h[jt], 0.f));
    }
  }
  // intra-wave ordering: compiler lgkmcnt; no barrier.

  // ---- load ALL phase2 A-frags once ----
  bf16x8 af0[8], af1[8];
  #pragma unroll
  for (int mt = 0; mt < 8; ++mt) {
    af0[mt] = *(const bf16x8*)&h2s[(mt * 16 + lr) * 72 + lg * 8];
    af1[mt] = *(const bf16x8*)&h2s[(mt * 16 + lr) * 72 + 32 + lg * 8];
  }

  // ---- phase2 + softmax: 16 ct-iterations, MFMA from registers ----
  #pragma unroll 4
  for (int ct = 0; ct < 16; ++ct) {
    const int c = ct * 16 + lr;
    bf16x8 bfr0 = *(const bf16x8*)&mw3b[(size_t)c * 64 + lg * 8];
    bf16x8 bfr1 = *(const bf16x8*)&mw3b[(size_t)c * 64 + 32 + lg * 8];
    f32x4 acc[8];
    #pragma unroll
    for (int mt = 0; mt < 8; ++mt) acc[mt] = f32x4{0.f, 0.f, 0.f, 0.f};
    #pragma unroll
    for (int mt = 0; mt < 8; ++mt) {
      acc[mt] = __builtin_amdgcn_mfma_f32_16x16x32_bf16(af0[mt], bfr0, acc[mt], 0, 0, 0);
      acc[mt] = __builtin_amdgcn_mfma_f32_16x16x32_bf16(af1[mt], bfr1, acc[mt], 0, 0, 0);
    }
    const float g = mg3[c];
    const float gs = g * LOG2E;
    const float cs = (g * mb3[c] + mbe3[c]) * LOG2E;
    f32x4 sm4 = f32x4{0.f, 0.f, 0.f, 0.f};
    f32x4 wb4 = f32x4{0.f, 0.f, 0.f, 0.f};
    #pragma unroll
    for (int mt = 0; mt < 8; ++mt) {
      ushort4_t bv4 = *(const ushort4_t*)&BmTb[(size_t)c * 128 + mt * 16 + 4 * lg];
      #pragma unroll
      for (int r = 0; r < 4; ++r) {
        float t = fmaf(gs, acc[mt][r], cs);
        float p = __builtin_amdgcn_exp2f(__builtin_amdgcn_fmed3f(t, 0.f, 80.f));
        sm4[r] += p;
        wb4[r] = fmaf(p, b2f(bv4[r]), wb4[r]);
      }
    }
    float sm = (sm4[0] + sm4[1]) + (sm4[2] + sm4[3]);
    float wb = (wb4[0] + wb4[1]) + (wb4[2] + wb4[3]);
    sm += __shfl_xor(sm, 16, 64);  wb += __shfl_xor(wb, 16, 64);
    sm += __shfl_xor(sm, 32, 64);  wb += __shfl_xor(wb, 32, 64);
    if (lg == 0)
      attL[c] = A[(size_t)n * 256 + c] - wb / sm;
  }

  // ---- fc (intra-wave): lane covers c = lane*4..lane*4+3 ----
  {
    float4_t av = *(const float4_t*)&attL[lane * 4];
    #pragma unroll
    for (int o = 0; o < 13; ++o) {
      float4_t wv = *(const float4_t*)&fcw[(size_t)o * 256 + lane * 4];
      float s = av[0] * wv[0];
      s = fmaf(av[1], wv[1], s);
      s = fmaf(av[2], wv[2], s);
      s = fmaf(av[3], wv[3], s);
      #pragma unroll
      for (int st = 1; st <= 32; st <<= 1) s += __shfl_xor(s, st, 64);
      if (lane == 0) outp[(size_t)n * 13 + o] = s + fcb[o];
    }
  }
}

extern "C" void kernel_launch(void* const* d_in, const int* in_sizes, int n_in,
                              void* d_out, int out_size, void* d_ws, size_t ws_size,
                              hipStream_t stream)
{
  const float* ext = (const float*)d_in[0];
  const float* lab = (const float*)d_in[1];
  const float* w1a = (const float*)d_in[2];
  const float* b1a = (const float*)d_in[3];
  const float* g1a = (const float*)d_in[4];
  const float* be1a= (const float*)d_in[5];
  const float* w1b = (const float*)d_in[6];
  const float* b1b = (const float*)d_in[7];
  const float* g1b = (const float*)d_in[8];
  const float* be1b= (const float*)d_in[9];
  const float* w2a = (const float*)d_in[10];
  const float* b2a = (const float*)d_in[11];
  const float* g2a = (const float*)d_in[12];
  const float* be2a= (const float*)d_in[13];
  const float* w2b = (const float*)d_in[14];
  const float* b2b = (const float*)d_in[15];
  const float* g2b = (const float*)d_in[16];
  const float* be2b= (const float*)d_in[17];
  const float* mw1 = (const float*)d_in[18];
  const float* mb1 = (const float*)d_in[19];
  const float* mg1 = (const float*)d_in[20];
  const float* mbe1= (const float*)d_in[21];
  const float* mw2 = (const float*)d_in[22];
  const float* mb2 = (const float*)d_in[23];
  const float* mg2 = (const float*)d_in[24];
  const float* mbe2= (const float*)d_in[25];
  const float* mw3 = (const float*)d_in[26];
  const float* mb3 = (const float*)d_in[27];
  const float* mg3 = (const float*)d_in[28];
  const float* mbe3= (const float*)d_in[29];
  const float* fcw = (const float*)d_in[30];
  const float* fcb = (const float*)d_in[31];

  char* ws = (char*)d_ws;
  ushort_t* Y1ab = (ushort_t*)(ws);                       // [0,2M) bf16 (dead after enc2)
  float*    PA2  = (float*)(ws);                          // [0,256K) written by proj
  float*    PB2  = (float*)(ws + 262144);                 // [256K,272K)
  float*    Aenc = (float*)(ws + (2u << 20));             // [2M,4M)
  char* b5 = ws + (4u << 20);
  ushort_t* mw2b  = (ushort_t*)(b5);                      // 64x32 bf16
  ushort_t* mw3b  = (ushort_t*)(b5 + 4096);               // 256x64 bf16
  ushort_t* Y1bb  = (ushort_t*)(b5 + 36864);              // 128x512 bf16
  float*    Benc  = (float*)(b5 + 167936);                // 128x256 f32
  ushort_t* BencTb= (ushort_t*)(b5 + 299008);             // 256x128 bf16 (64KB)

  enc_mfma<0, 0, 1><<<dim3(68, 16), 256, 0, stream>>>(
      (const void*)ext, (const void*)w1a, b1a, g1a, be1a, (void*)Y1ab,
      (const void*)lab, (const void*)w2a, b2a, g2a, be2a, (void*)Y1bb,
      (ushort_t*)nullptr, 512, 352, 64);
  enc_mfma<1, 0, 0><<<dim3(68, 8), 256, 0, stream>>>(
      (const void*)Y1ab, (const void*)w1b, b1b, g1b, be1b, (void*)Aenc,
      (const void*)Y1bb, (const void*)w2b, b2b, g2b, be2b, (void*)Benc,
      BencTb, 256, 512, 64);
  proj32<<<553, 256, 0, stream>>>(Aenc, Benc, mw1, mb1, mg1, mbe1, PA2, PB2, 512,
                                  mw2, mw3, mw2b, mw3b);
  main_attn<<<512, 256, 0, stream>>>(PA2, PB2, Aenc, BencTb,
                                     mw2b, mb2, mg2, mbe2, mw3b, mb3, mg3, mbe3,
                                     fcw, fcb, (float*)d_out);
}

// Round 27
// 81.534 us; speedup vs baseline: 1.0964x; 1.0104x over previous
//
#include <hip/hip_runtime.h>
#include <stdint.h>

// N=2048, M=128, D_IN=352, H1=512, D=256, OUT_C=13.  All device tensors FLOAT32.
// Round 27: R26 config + ONE change: phase2 ct-loop paired (ct, ct+8) -> two
// semantically independent chains per iteration (MFMA/exp2/gather/reduce x2).
// Unlike R16's hoists (compiler re-sank them), the second chain is required
// work -> scheduler must keep both live -> chain-overlap ILP.  Est VGPR ~195
// (<256 @ (256,2), spill tripwire = WRITE_SIZE).  All else = R26 verbatim.

typedef __attribute__((ext_vector_type(4))) float float4_t;
typedef __attribute__((ext_vector_type(4))) float f32x4;
typedef __attribute__((ext_vector_type(8))) short bf16x8;
typedef __attribute__((ext_vector_type(8))) unsigned short ushort8_t;
typedef __attribute__((ext_vector_type(4))) unsigned short ushort4_t;
typedef unsigned short ushort_t;

__device__ __forceinline__ float b2f(unsigned short u) {
  union { unsigned int i; float f; } v; v.i = ((unsigned int)u) << 16; return v.f;
}
__device__ __forceinline__ unsigned short f2b(float f) {
  union { float f; unsigned int i; } v; v.f = f;
  unsigned int x = v.i;
  return (unsigned short)((x + 0x7FFFu + ((x >> 16) & 1u)) >> 16);
}

template<int ISBF>
__device__ __forceinline__ ushort8_t ld8(const void* base, size_t idx) {
  if constexpr (ISBF) {
    return *(const ushort8_t*)((const ushort_t*)base + idx);
  } else {
    const float* p = (const float*)base + idx;
    float4_t v0 = *(const float4_t*)p;
    float4_t v1 = *(const float4_t*)(p + 4);
    ushort8_t u;
    #pragma unroll
    for (int e = 0; e < 4; ++e) { u[e] = f2b(v0[e]); u[4 + e] = f2b(v1[e]); }
    return u;
  }
}

// ---------- MFMA encoder: 32x32 tile, K_STEP=64 dbuf (2 MFMA/wave/barrier) ----------
template<int XBF, int WBF, int OUT_BF16>
__global__ __launch_bounds__(256) void enc_mfma(
    const void* __restrict__ XA, const void* __restrict__ WA,
    const float* __restrict__ bA, const float* __restrict__ gA, const float* __restrict__ beA,
    void* __restrict__ YA,
    const void* __restrict__ XB, const void* __restrict__ WB,
    const float* __restrict__ bB, const float* __restrict__ gB, const float* __restrict__ beB,
    void* __restrict__ YB, ushort_t* __restrict__ YBTb,
    int J, int K, int nbxA)
{
  __shared__ ushort_t Xs[2][32][72];
  __shared__ ushort_t Ws[2][32][72];
  const int bx = blockIdx.x, by = blockIdx.y;
  const void* X; const void* W;
  const float *bb, *gg, *bev; void* Y; int i0, isB;
  if (bx < nbxA) { X = XA; W = WA; bb = bA; gg = gA; bev = beA; Y = YA; i0 = bx * 32; isB = 0; }
  else           { X = XB; W = WB; bb = bB; gg = gB; bev = beB; Y = YB; i0 = (bx - nbxA) * 32; isB = 1; }
  const int j0 = by * 32;
  const int tid = threadIdx.x, w = tid >> 6, lane = tid & 63, lg = lane >> 4, lr = lane & 15;
  const int mt = w >> 1, ct = w & 1;
  const int row = tid >> 3, k8 = (tid & 7) * 8;   // 32 rows x 8 chunks

  f32x4 acc = f32x4{0.f, 0.f, 0.f, 0.f};

  ushort8_t xv = ld8<XBF>(X, (size_t)(i0 + row) * K + k8);
  ushort8_t wv = ld8<WBF>(W, (size_t)(j0 + row) * K + k8);
  for (int kt = 0; kt < K; kt += 64) {
    const int buf = (kt >> 6) & 1;
    *(ushort8_t*)&Xs[buf][row][k8] = xv;
    *(ushort8_t*)&Ws[buf][row][k8] = wv;
    __syncthreads();
    if (kt + 64 < K && kt + 64 + k8 < K) {
      xv = ld8<XBF>(X, (size_t)(i0 + row) * K + kt + 64 + k8);
      wv = ld8<WBF>(W, (size_t)(j0 + row) * K + kt + 64 + k8);
    }
    bf16x8 af0 = *(const bf16x8*)&Xs[buf][mt * 16 + lr][lg * 8];
    bf16x8 bf0 = *(const bf16x8*)&Ws[buf][ct * 16 + lr][lg * 8];
    acc = __builtin_amdgcn_mfma_f32_16x16x32_bf16(af0, bf0, acc, 0, 0, 0);
    if (kt + 32 < K) {
      bf16x8 af1 = *(const bf16x8*)&Xs[buf][mt * 16 + lr][32 + lg * 8];
      bf16x8 bf1 = *(const bf16x8*)&Ws[buf][ct * 16 + lr][32 + lg * 8];
      acc = __builtin_amdgcn_mfma_f32_16x16x32_bf16(af1, bf1, acc, 0, 0, 0);
    }
  }
  const int c = j0 + ct * 16 + lr;
  const float g = gg[c], bv = bb[c], ev = bev[c];
  #pragma unroll
  for (int r = 0; r < 4; ++r) {
    const int rowo = i0 + mt * 16 + 4 * lg + r;
    float t = fmaxf(g * (acc[r] + bv) + ev, 0.f);
    if (OUT_BF16) ((ushort_t*)Y)[(size_t)rowo * J + c] = f2b(t);
    else {
      ((float*)Y)[(size_t)rowo * J + c] = t;
      if (isB && YBTb) YBTb[(size_t)c * 128 + rowo] = f2b(t);
    }
  }
}

// ---------- proj: P = fold(X @ mw1^T); 4 rows/block, split-K-2; + cvt tail ----------
__global__ __launch_bounds__(256) void proj32(
    const float* __restrict__ Aenc, const float* __restrict__ Benc,
    const float* __restrict__ mw1, const float* __restrict__ mb1,
    const float* __restrict__ mg1, const float* __restrict__ mbe1,
    float* __restrict__ PA2, float* __restrict__ PB2, int nbxA,
    const float* __restrict__ mw2, const float* __restrict__ mw3,
    ushort_t* __restrict__ mw2b, ushort_t* __restrict__ mw3b)
{
  __shared__ float ps[4][32];
  const int tid = threadIdx.x, bx = blockIdx.x;
  if (bx >= nbxA + 32) {
    const int g = (bx - nbxA - 32) * 256 + tid;
    const float* s; ushort_t* d; int j;
    if (g < 256) { s = mw2; d = mw2b; j = g; }
    else         { s = mw3; d = mw3b; j = g - 256; }
    float4_t v0 = *(const float4_t*)&s[(size_t)j * 8];
    float4_t v1 = *(const float4_t*)&s[(size_t)j * 8 + 4];
    ushort8_t u;
    #pragma unroll
    for (int e = 0; e < 4; ++e) { u[e] = f2b(v0[e]); u[4 + e] = f2b(v1[e]); }
    *(ushort8_t*)&d[(size_t)j * 8] = u;
    return;
  }
  const float* X; float* P; int n0, wb;
  if (bx < nbxA) { X = Aenc; P = PA2; n0 = bx * 4; wb = 1; }
  else           { X = Benc; P = PB2; n0 = (bx - nbxA) * 4; wb = 0; }
  const int k = tid & 31, r = (tid >> 5) & 3, half = tid >> 7;
  const int n = n0 + r;
  const float* xp = &X[(size_t)n * 256 + half * 128];
  const float* wp = &mw1[k * 256 + half * 128];
  float s = 0.f;
  #pragma unroll 8
  for (int q = 0; q < 128; q += 4) {
    float4_t xv = *(const float4_t*)&xp[q];
    float4_t wv = *(const float4_t*)&wp[q];
    #pragma unroll
    for (int e = 0; e < 4; ++e) s = fmaf(xv[e], wv[e], s);
  }
  if (half == 1) ps[r][k] = s;
  __syncthreads();
  if (half == 0) {
    s += ps[r][k];
    P[(size_t)n * 32 + k] = wb ? (mg1[k] * (s + mb1[k]) + mbe1[k]) : (mg1[k] * s);
  }
}

// ---------- fused main kernel: one wave = one n, zero barriers, PAIRED ct chains ----------
// MFMA 16x16x32_bf16: A frag m=lane&15,k=(lane>>4)*8+e; B frag c=lane&15,same k;
// C/D col=lane&15,row=(lane>>4)*4+reg.
// Per-wave slab: h2[128][72] bf16 + att[256] f32 = 19456B; 4 waves/block = 77824B.
// Phase2 processes ct and ct+8 together: two independent MFMA/softmax chains per
// iteration -> scheduler overlaps c1's MFMAs under c0's exp2/L2 stalls.
__global__ __launch_bounds__(256, 2) void main_attn(
    const float* __restrict__ PA2, const float* __restrict__ PB2,
    const float* __restrict__ A, const ushort_t* __restrict__ BmTb,
    const ushort_t* __restrict__ mw2b, const float* __restrict__ mb2,
    const float* __restrict__ mg2, const float* __restrict__ mbe2,
    const ushort_t* __restrict__ mw3b, const float* __restrict__ mb3,
    const float* __restrict__ mg3, const float* __restrict__ mbe3,
    const float* __restrict__ fcw, const float* __restrict__ fcb,
    float* __restrict__ outp)
{
  __shared__ __align__(16) char smem[77824];
  const int tid = threadIdx.x;
  const int w = tid >> 6, lane = tid & 63, lg = lane >> 4, lr = lane & 15;
  const int n = blockIdx.x * 4 + w;
  ushort_t* h2s = (ushort_t*)(smem + w * 19456);
  float* attL   = (float*)(smem + w * 19456 + 18432);
  const float LOG2E = 1.4426950408889634f;

  // ---- phase1: h2[m][j] = relu(g2*(relu(PA2[n]-PB2[m]) @ mw2^T + b2) + be2) ----
  {
    bf16x8 b1[4];
    float g2h[4], b2h[4], e2h[4];
    #pragma unroll
    for (int jt = 0; jt < 4; ++jt) {
      b1[jt] = *(const bf16x8*)&mw2b[(jt * 16 + lr) * 32 + lg * 8];
      const int j = jt * 16 + lr;
      g2h[jt] = mg2[j]; b2h[jt] = mb2[j]; e2h[jt] = mbe2[j];
    }
    const float* pa = &PA2[(size_t)n * 32 + lg * 8];
    float4_t pa0 = *(const float4_t*)pa;
    float4_t pa1 = *(const float4_t*)(pa + 4);
    #pragma unroll
    for (int mt = 0; mt < 8; ++mt) {
      const float* pb = &PB2[(size_t)(mt * 16 + lr) * 32 + lg * 8];
      float4_t pb0 = *(const float4_t*)pb;
      float4_t pb1 = *(const float4_t*)(pb + 4);
      bf16x8 a1;
      #pragma unroll
      for (int e = 0; e < 4; ++e) {
        a1[e]     = (short)f2b(fmaxf(pa0[e] - pb0[e], 0.f));
        a1[4 + e] = (short)f2b(fmaxf(pa1[e] - pb1[e], 0.f));
      }
      f32x4 acc1[4];
      #pragma unroll
      for (int jt = 0; jt < 4; ++jt) acc1[jt] = f32x4{0.f, 0.f, 0.f, 0.f};
      #pragma unroll
      for (int jt = 0; jt < 4; ++jt)
        acc1[jt] = __builtin_amdgcn_mfma_f32_16x16x32_bf16(a1, b1[jt], acc1[jt], 0, 0, 0);
      #pragma unroll
      for (int jt = 0; jt < 4; ++jt)
        #pragma unroll
        for (int r = 0; r < 4; ++r)
          h2s[(mt * 16 + 4 * lg + r) * 72 + jt * 16 + lr] =
              f2b(fmaxf(g2h[jt] * (acc1[jt][r] + b2h[jt]) + e2h[jt], 0.f));
    }
  }
  // intra-wave ordering: compiler lgkmcnt; no barrier.

  // ---- load ALL phase2 A-frags once ----
  bf16x8 af0[8], af1[8];
  #pragma unroll
  for (int mt = 0; mt < 8; ++mt) {
    af0[mt] = *(const bf16x8*)&h2s[(mt * 16 + lr) * 72 + lg * 8];
    af1[mt] = *(const bf16x8*)&h2s[(mt * 16 + lr) * 72 + 32 + lg * 8];
  }

  // ---- phase2 + softmax: 8 iterations, each handles ct and ct+8 (2 chains) ----
  #pragma unroll 2
  for (int ct = 0; ct < 8; ++ct) {
    const int c0 = ct * 16 + lr;
    const int c1 = (ct + 8) * 16 + lr;
    bf16x8 bfr0a = *(const bf16x8*)&mw3b[(size_t)c0 * 64 + lg * 8];
    bf16x8 bfr1a = *(const bf16x8*)&mw3b[(size_t)c0 * 64 + 32 + lg * 8];
    bf16x8 bfr0b = *(const bf16x8*)&mw3b[(size_t)c1 * 64 + lg * 8];
    bf16x8 bfr1b = *(const bf16x8*)&mw3b[(size_t)c1 * 64 + 32 + lg * 8];
    f32x4 accA[8], accB[8];
    #pragma unroll
    for (int mt = 0; mt < 8; ++mt) {
      accA[mt] = f32x4{0.f, 0.f, 0.f, 0.f};
      accB[mt] = f32x4{0.f, 0.f, 0.f, 0.f};
    }
    #pragma unroll
    for (int mt = 0; mt < 8; ++mt) {
      accA[mt] = __builtin_amdgcn_mfma_f32_16x16x32_bf16(af0[mt], bfr0a, accA[mt], 0, 0, 0);
      accB[mt] = __builtin_amdgcn_mfma_f32_16x16x32_bf16(af0[mt], bfr0b, accB[mt], 0, 0, 0);
      accA[mt] = __builtin_amdgcn_mfma_f32_16x16x32_bf16(af1[mt], bfr1a, accA[mt], 0, 0, 0);
      accB[mt] = __builtin_amdgcn_mfma_f32_16x16x32_bf16(af1[mt], bfr1b, accB[mt], 0, 0, 0);
    }
    const float gA_ = mg3[c0], gB_ = mg3[c1];
    const float gsA = gA_ * LOG2E, gsB = gB_ * LOG2E;
    const float csA = (gA_ * mb3[c0] + mbe3[c0]) * LOG2E;
    const float csB = (gB_ * mb3[c1] + mbe3[c1]) * LOG2E;
    f32x4 smA = f32x4{0.f, 0.f, 0.f, 0.f};
    f32x4 wbA = f32x4{0.f, 0.f, 0.f, 0.f};
    f32x4 smB = f32x4{0.f, 0.f, 0.f, 0.f};
    f32x4 wbB = f32x4{0.f, 0.f, 0.f, 0.f};
    #pragma unroll
    for (int mt = 0; mt < 8; ++mt) {
      ushort4_t bvA = *(const ushort4_t*)&BmTb[(size_t)c0 * 128 + mt * 16 + 4 * lg];
      ushort4_t bvB = *(const ushort4_t*)&BmTb[(size_t)c1 * 128 + mt * 16 + 4 * lg];
      #pragma unroll
      for (int r = 0; r < 4; ++r) {
        float tA = fmaf(gsA, accA[mt][r], csA);
        float pA = __builtin_amdgcn_exp2f(__builtin_amdgcn_fmed3f(tA, 0.f, 80.f));
        smA[r] += pA;
        wbA[r] = fmaf(pA, b2f(bvA[r]), wbA[r]);
        float tB = fmaf(gsB, accB[mt][r], csB);
        float pB = __builtin_amdgcn_exp2f(__builtin_amdgcn_fmed3f(tB, 0.f, 80.f));
        smB[r] += pB;
        wbB[r] = fmaf(pB, b2f(bvB[r]), wbB[r]);
      }
    }
    float sA = (smA[0] + smA[1]) + (smA[2] + smA[3]);
    float wA_ = (wbA[0] + wbA[1]) + (wbA[2] + wbA[3]);
    float sB = (smB[0] + smB[1]) + (smB[2] + smB[3]);
    float wB_ = (wbB[0] + wbB[1]) + (wbB[2] + wbB[3]);
    sA += __shfl_xor(sA, 16, 64);  wA_ += __shfl_xor(wA_, 16, 64);
    sB += __shfl_xor(sB, 16, 64);  wB_ += __shfl_xor(wB_, 16, 64);
    sA += __shfl_xor(sA, 32, 64);  wA_ += __shfl_xor(wA_, 32, 64);
    sB += __shfl_xor(sB, 32, 64);  wB_ += __shfl_xor(wB_, 32, 64);
    if (lg == 0) {
      attL[c0] = A[(size_t)n * 256 + c0] - wA_ / sA;
      attL[c1] = A[(size_t)n * 256 + c1] - wB_ / sB;
    }
  }

  // ---- fc (intra-wave): lane covers c = lane*4..lane*4+3 ----
  {
    float4_t av = *(const float4_t*)&attL[lane * 4];
    #pragma unroll
    for (int o = 0; o < 13; ++o) {
      float4_t wv = *(const float4_t*)&fcw[(size_t)o * 256 + lane * 4];
      float s = av[0] * wv[0];
      s = fmaf(av[1], wv[1], s);
      s = fmaf(av[2], wv[2], s);
      s = fmaf(av[3], wv[3], s);
      #pragma unroll
      for (int st = 1; st <= 32; st <<= 1) s += __shfl_xor(s, st, 64);
      if (lane == 0) outp[(size_t)n * 13 + o] = s + fcb[o];
    }
  }
}

extern "C" void kernel_launch(void* const* d_in, const int* in_sizes, int n_in,
                              void* d_out, int out_size, void* d_ws, size_t ws_size,
                              hipStream_t stream)
{
  const float* ext = (const float*)d_in[0];
  const float* lab = (const float*)d_in[1];
  const float* w1a = (const float*)d_in[2];
  const float* b1a = (const float*)d_in[3];
  const float* g1a = (const float*)d_in[4];
  const float* be1a= (const float*)d_in[5];
  const float* w1b = (const float*)d_in[6];
  const float* b1b = (const float*)d_in[7];
  const float* g1b = (const float*)d_in[8];
  const float* be1b= (const float*)d_in[9];
  const float* w2a = (const float*)d_in[10];
  const float* b2a = (const float*)d_in[11];
  const float* g2a = (const float*)d_in[12];
  const float* be2a= (const float*)d_in[13];
  const float* w2b = (const float*)d_in[14];
  const float* b2b = (const float*)d_in[15];
  const float* g2b = (const float*)d_in[16];
  const float* be2b= (const float*)d_in[17];
  const float* mw1 = (const float*)d_in[18];
  const float* mb1 = (const float*)d_in[19];
  const float* mg1 = (const float*)d_in[20];
  const float* mbe1= (const float*)d_in[21];
  const float* mw2 = (const float*)d_in[22];
  const float* mb2 = (const float*)d_in[23];
  const float* mg2 = (const float*)d_in[24];
  const float* mbe2= (const float*)d_in[25];
  const float* mw3 = (const float*)d_in[26];
  const float* mb3 = (const float*)d_in[27];
  const float* mg3 = (const float*)d_in[28];
  const float* mbe3= (const float*)d_in[29];
  const float* fcw = (const float*)d_in[30];
  const float* fcb = (const float*)d_in[31];

  char* ws = (char*)d_ws;
  ushort_t* Y1ab = (ushort_t*)(ws);                       // [0,2M) bf16 (dead after enc2)
  float*    PA2  = (float*)(ws);                          // [0,256K) written by proj
  float*    PB2  = (float*)(ws + 262144);                 // [256K,272K)
  float*    Aenc = (float*)(ws + (2u << 20));             // [2M,4M)
  char* b5 = ws + (4u << 20);
  ushort_t* mw2b  = (ushort_t*)(b5);                      // 64x32 bf16
  ushort_t* mw3b  = (ushort_t*)(b5 + 4096);               // 256x64 bf16
  ushort_t* Y1bb  = (ushort_t*)(b5 + 36864);              // 128x512 bf16
  float*    Benc  = (float*)(b5 + 167936);                // 128x256 f32
  ushort_t* BencTb= (ushort_t*)(b5 + 299008);             // 256x128 bf16 (64KB)

  enc_mfma<0, 0, 1><<<dim3(68, 16), 256, 0, stream>>>(
      (const void*)ext, (const void*)w1a, b1a, g1a, be1a, (void*)Y1ab,
      (const void*)lab, (const void*)w2a, b2a, g2a, be2a, (void*)Y1bb,
      (ushort_t*)nullptr, 512, 352, 64);
  enc_mfma<1, 0, 0><<<dim3(68, 8), 256, 0, stream>>>(
      (const void*)Y1ab, (const void*)w1b, b1b, g1b, be1b, (void*)Aenc,
      (const void*)Y1bb, (const void*)w2b, b2b, g2b, be2b, (void*)Benc,
      BencTb, 256, 512, 64);
  proj32<<<553, 256, 0, stream>>>(Aenc, Benc, mw1, mb1, mg1, mbe1, PA2, PB2, 512,
                                  mw2, mw3, mw2b, mw3b);
  main_attn<<<512, 256, 0, stream>>>(PA2, PB2, Aenc, BencTb,
                                     mw2b, mb2, mg2, mbe2, mw3b, mb3, mg3, mbe3,
                                     fcw, fcb, (float*)d_out);
}

// Round 28
// 80.165 us; speedup vs baseline: 1.1152x; 1.0171x over previous
//
#include <hip/hip_runtime.h>
#include <stdint.h>

// N=2048, M=128, D_IN=352, H1=512, D=256, OUT_C=13.  All device tensors FLOAT32.
// Round 28: R27 (best, 81.53us) + paired fc epilogue (o,o+1 dual reduce chains,
// 13 serial wave-reduces -> 7 paired).  All else = R27 verbatim.
// Config summary: algebra folds (conv1 -> PA2/PB2; softmax-sums-to-1 -> att =
// A - wB/s), no-max exp2 softmax, zero-barrier wave-per-n main kernel with
// resident A-frags + paired phase2 chains; 32x32 K64-dbuf MFMA encoders; proj+cvt.

typedef __attribute__((ext_vector_type(4))) float float4_t;
typedef __attribute__((ext_vector_type(4))) float f32x4;
typedef __attribute__((ext_vector_type(8))) short bf16x8;
typedef __attribute__((ext_vector_type(8))) unsigned short ushort8_t;
typedef __attribute__((ext_vector_type(4))) unsigned short ushort4_t;
typedef unsigned short ushort_t;

__device__ __forceinline__ float b2f(unsigned short u) {
  union { unsigned int i; float f; } v; v.i = ((unsigned int)u) << 16; return v.f;
}
__device__ __forceinline__ unsigned short f2b(float f) {
  union { float f; unsigned int i; } v; v.f = f;
  unsigned int x = v.i;
  return (unsigned short)((x + 0x7FFFu + ((x >> 16) & 1u)) >> 16);
}

template<int ISBF>
__device__ __forceinline__ ushort8_t ld8(const void* base, size_t idx) {
  if constexpr (ISBF) {
    return *(const ushort8_t*)((const ushort_t*)base + idx);
  } else {
    const float* p = (const float*)base + idx;
    float4_t v0 = *(const float4_t*)p;
    float4_t v1 = *(const float4_t*)(p + 4);
    ushort8_t u;
    #pragma unroll
    for (int e = 0; e < 4; ++e) { u[e] = f2b(v0[e]); u[4 + e] = f2b(v1[e]); }
    return u;
  }
}

// ---------- MFMA encoder: 32x32 tile, K_STEP=64 dbuf (2 MFMA/wave/barrier) ----------
template<int XBF, int WBF, int OUT_BF16>
__global__ __launch_bounds__(256) void enc_mfma(
    const void* __restrict__ XA, const void* __restrict__ WA,
    const float* __restrict__ bA, const float* __restrict__ gA, const float* __restrict__ beA,
    void* __restrict__ YA,
    const void* __restrict__ XB, const void* __restrict__ WB,
    const float* __restrict__ bB, const float* __restrict__ gB, const float* __restrict__ beB,
    void* __restrict__ YB, ushort_t* __restrict__ YBTb,
    int J, int K, int nbxA)
{
  __shared__ ushort_t Xs[2][32][72];
  __shared__ ushort_t Ws[2][32][72];
  const int bx = blockIdx.x, by = blockIdx.y;
  const void* X; const void* W;
  const float *bb, *gg, *bev; void* Y; int i0, isB;
  if (bx < nbxA) { X = XA; W = WA; bb = bA; gg = gA; bev = beA; Y = YA; i0 = bx * 32; isB = 0; }
  else           { X = XB; W = WB; bb = bB; gg = gB; bev = beB; Y = YB; i0 = (bx - nbxA) * 32; isB = 1; }
  const int j0 = by * 32;
  const int tid = threadIdx.x, w = tid >> 6, lane = tid & 63, lg = lane >> 4, lr = lane & 15;
  const int mt = w >> 1, ct = w & 1;
  const int row = tid >> 3, k8 = (tid & 7) * 8;   // 32 rows x 8 chunks

  f32x4 acc = f32x4{0.f, 0.f, 0.f, 0.f};

  ushort8_t xv = ld8<XBF>(X, (size_t)(i0 + row) * K + k8);
  ushort8_t wv = ld8<WBF>(W, (size_t)(j0 + row) * K + k8);
  for (int kt = 0; kt < K; kt += 64) {
    const int buf = (kt >> 6) & 1;
    *(ushort8_t*)&Xs[buf][row][k8] = xv;
    *(ushort8_t*)&Ws[buf][row][k8] = wv;
    __syncthreads();
    if (kt + 64 < K && kt + 64 + k8 < K) {
      xv = ld8<XBF>(X, (size_t)(i0 + row) * K + kt + 64 + k8);
      wv = ld8<WBF>(W, (size_t)(j0 + row) * K + kt + 64 + k8);
    }
    bf16x8 af0 = *(const bf16x8*)&Xs[buf][mt * 16 + lr][lg * 8];
    bf16x8 bf0 = *(const bf16x8*)&Ws[buf][ct * 16 + lr][lg * 8];
    acc = __builtin_amdgcn_mfma_f32_16x16x32_bf16(af0, bf0, acc, 0, 0, 0);
    if (kt + 32 < K) {
      bf16x8 af1 = *(const bf16x8*)&Xs[buf][mt * 16 + lr][32 + lg * 8];
      bf16x8 bf1 = *(const bf16x8*)&Ws[buf][ct * 16 + lr][32 + lg * 8];
      acc = __builtin_amdgcn_mfma_f32_16x16x32_bf16(af1, bf1, acc, 0, 0, 0);
    }
  }
  const int c = j0 + ct * 16 + lr;
  const float g = gg[c], bv = bb[c], ev = bev[c];
  #pragma unroll
  for (int r = 0; r < 4; ++r) {
    const int rowo = i0 + mt * 16 + 4 * lg + r;
    float t = fmaxf(g * (acc[r] + bv) + ev, 0.f);
    if (OUT_BF16) ((ushort_t*)Y)[(size_t)rowo * J + c] = f2b(t);
    else {
      ((float*)Y)[(size_t)rowo * J + c] = t;
      if (isB && YBTb) YBTb[(size_t)c * 128 + rowo] = f2b(t);
    }
  }
}

// ---------- proj: P = fold(X @ mw1^T); 4 rows/block, split-K-2; + cvt tail ----------
__global__ __launch_bounds__(256) void proj32(
    const float* __restrict__ Aenc, const float* __restrict__ Benc,
    const float* __restrict__ mw1, const float* __restrict__ mb1,
    const float* __restrict__ mg1, const float* __restrict__ mbe1,
    float* __restrict__ PA2, float* __restrict__ PB2, int nbxA,
    const float* __restrict__ mw2, const float* __restrict__ mw3,
    ushort_t* __restrict__ mw2b, ushort_t* __restrict__ mw3b)
{
  __shared__ float ps[4][32];
  const int tid = threadIdx.x, bx = blockIdx.x;
  if (bx >= nbxA + 32) {
    const int g = (bx - nbxA - 32) * 256 + tid;
    const float* s; ushort_t* d; int j;
    if (g < 256) { s = mw2; d = mw2b; j = g; }
    else         { s = mw3; d = mw3b; j = g - 256; }
    float4_t v0 = *(const float4_t*)&s[(size_t)j * 8];
    float4_t v1 = *(const float4_t*)&s[(size_t)j * 8 + 4];
    ushort8_t u;
    #pragma unroll
    for (int e = 0; e < 4; ++e) { u[e] = f2b(v0[e]); u[4 + e] = f2b(v1[e]); }
    *(ushort8_t*)&d[(size_t)j * 8] = u;
    return;
  }
  const float* X; float* P; int n0, wb;
  if (bx < nbxA) { X = Aenc; P = PA2; n0 = bx * 4; wb = 1; }
  else           { X = Benc; P = PB2; n0 = (bx - nbxA) * 4; wb = 0; }
  const int k = tid & 31, r = (tid >> 5) & 3, half = tid >> 7;
  const int n = n0 + r;
  const float* xp = &X[(size_t)n * 256 + half * 128];
  const float* wp = &mw1[k * 256 + half * 128];
  float s = 0.f;
  #pragma unroll 8
  for (int q = 0; q < 128; q += 4) {
    float4_t xv = *(const float4_t*)&xp[q];
    float4_t wv = *(const float4_t*)&wp[q];
    #pragma unroll
    for (int e = 0; e < 4; ++e) s = fmaf(xv[e], wv[e], s);
  }
  if (half == 1) ps[r][k] = s;
  __syncthreads();
  if (half == 0) {
    s += ps[r][k];
    P[(size_t)n * 32 + k] = wb ? (mg1[k] * (s + mb1[k]) + mbe1[k]) : (mg1[k] * s);
  }
}

// ---------- fused main kernel: one wave = one n, zero barriers, paired chains ----------
// MFMA 16x16x32_bf16: A frag m=lane&15,k=(lane>>4)*8+e; B frag c=lane&15,same k;
// C/D col=lane&15,row=(lane>>4)*4+reg.
// Per-wave slab: h2[128][72] bf16 + att[256] f32 = 19456B; 4 waves/block = 77824B.
__global__ __launch_bounds__(256, 2) void main_attn(
    const float* __restrict__ PA2, const float* __restrict__ PB2,
    const float* __restrict__ A, const ushort_t* __restrict__ BmTb,
    const ushort_t* __restrict__ mw2b, const float* __restrict__ mb2,
    const float* __restrict__ mg2, const float* __restrict__ mbe2,
    const ushort_t* __restrict__ mw3b, const float* __restrict__ mb3,
    const float* __restrict__ mg3, const float* __restrict__ mbe3,
    const float* __restrict__ fcw, const float* __restrict__ fcb,
    float* __restrict__ outp)
{
  __shared__ __align__(16) char smem[77824];
  const int tid = threadIdx.x;
  const int w = tid >> 6, lane = tid & 63, lg = lane >> 4, lr = lane & 15;
  const int n = blockIdx.x * 4 + w;
  ushort_t* h2s = (ushort_t*)(smem + w * 19456);
  float* attL   = (float*)(smem + w * 19456 + 18432);
  const float LOG2E = 1.4426950408889634f;

  // ---- phase1: h2[m][j] = relu(g2*(relu(PA2[n]-PB2[m]) @ mw2^T + b2) + be2) ----
  {
    bf16x8 b1[4];
    float g2h[4], b2h[4], e2h[4];
    #pragma unroll
    for (int jt = 0; jt < 4; ++jt) {
      b1[jt] = *(const bf16x8*)&mw2b[(jt * 16 + lr) * 32 + lg * 8];
      const int j = jt * 16 + lr;
      g2h[jt] = mg2[j]; b2h[jt] = mb2[j]; e2h[jt] = mbe2[j];
    }
    const float* pa = &PA2[(size_t)n * 32 + lg * 8];
    float4_t pa0 = *(const float4_t*)pa;
    float4_t pa1 = *(const float4_t*)(pa + 4);
    #pragma unroll
    for (int mt = 0; mt < 8; ++mt) {
      const float* pb = &PB2[(size_t)(mt * 16 + lr) * 32 + lg * 8];
      float4_t pb0 = *(const float4_t*)pb;
      float4_t pb1 = *(const float4_t*)(pb + 4);
      bf16x8 a1;
      #pragma unroll
      for (int e = 0; e < 4; ++e) {
        a1[e]     = (short)f2b(fmaxf(pa0[e] - pb0[e], 0.f));
        a1[4 + e] = (short)f2b(fmaxf(pa1[e] - pb1[e], 0.f));
      }
      f32x4 acc1[4];
      #pragma unroll
      for (int jt = 0; jt < 4; ++jt) acc1[jt] = f32x4{0.f, 0.f, 0.f, 0.f};
      #pragma unroll
      for (int jt = 0; jt < 4; ++jt)
        acc1[jt] = __builtin_amdgcn_mfma_f32_16x16x32_bf16(a1, b1[jt], acc1[jt], 0, 0, 0);
      #pragma unroll
      for (int jt = 0; jt < 4; ++jt)
        #pragma unroll
        for (int r = 0; r < 4; ++r)
          h2s[(mt * 16 + 4 * lg + r) * 72 + jt * 16 + lr] =
              f2b(fmaxf(g2h[jt] * (acc1[jt][r] + b2h[jt]) + e2h[jt], 0.f));
    }
  }
  // intra-wave ordering: compiler lgkmcnt; no barrier.

  // ---- load ALL phase2 A-frags once ----
  bf16x8 af0[8], af1[8];
  #pragma unroll
  for (int mt = 0; mt < 8; ++mt) {
    af0[mt] = *(const bf16x8*)&h2s[(mt * 16 + lr) * 72 + lg * 8];
    af1[mt] = *(const bf16x8*)&h2s[(mt * 16 + lr) * 72 + 32 + lg * 8];
  }

  // ---- phase2 + softmax: 8 iterations, each handles ct and ct+8 (2 chains) ----
  #pragma unroll 2
  for (int ct = 0; ct < 8; ++ct) {
    const int c0 = ct * 16 + lr;
    const int c1 = (ct + 8) * 16 + lr;
    bf16x8 bfr0a = *(const bf16x8*)&mw3b[(size_t)c0 * 64 + lg * 8];
    bf16x8 bfr1a = *(const bf16x8*)&mw3b[(size_t)c0 * 64 + 32 + lg * 8];
    bf16x8 bfr0b = *(const bf16x8*)&mw3b[(size_t)c1 * 64 + lg * 8];
    bf16x8 bfr1b = *(const bf16x8*)&mw3b[(size_t)c1 * 64 + 32 + lg * 8];
    f32x4 accA[8], accB[8];
    #pragma unroll
    for (int mt = 0; mt < 8; ++mt) {
      accA[mt] = f32x4{0.f, 0.f, 0.f, 0.f};
      accB[mt] = f32x4{0.f, 0.f, 0.f, 0.f};
    }
    #pragma unroll
    for (int mt = 0; mt < 8; ++mt) {
      accA[mt] = __builtin_amdgcn_mfma_f32_16x16x32_bf16(af0[mt], bfr0a, accA[mt], 0, 0, 0);
      accB[mt] = __builtin_amdgcn_mfma_f32_16x16x32_bf16(af0[mt], bfr0b, accB[mt], 0, 0, 0);
      accA[mt] = __builtin_amdgcn_mfma_f32_16x16x32_bf16(af1[mt], bfr1a, accA[mt], 0, 0, 0);
      accB[mt] = __builtin_amdgcn_mfma_f32_16x16x32_bf16(af1[mt], bfr1b, accB[mt], 0, 0, 0);
    }
    const float gA_ = mg3[c0], gB_ = mg3[c1];
    const float gsA = gA_ * LOG2E, gsB = gB_ * LOG2E;
    const float csA = (gA_ * mb3[c0] + mbe3[c0]) * LOG2E;
    const float csB = (gB_ * mb3[c1] + mbe3[c1]) * LOG2E;
    f32x4 smA = f32x4{0.f, 0.f, 0.f, 0.f};
    f32x4 wbA = f32x4{0.f, 0.f, 0.f, 0.f};
    f32x4 smB = f32x4{0.f, 0.f, 0.f, 0.f};
    f32x4 wbB = f32x4{0.f, 0.f, 0.f, 0.f};
    #pragma unroll
    for (int mt = 0; mt < 8; ++mt) {
      ushort4_t bvA = *(const ushort4_t*)&BmTb[(size_t)c0 * 128 + mt * 16 + 4 * lg];
      ushort4_t bvB = *(const ushort4_t*)&BmTb[(size_t)c1 * 128 + mt * 16 + 4 * lg];
      #pragma unroll
      for (int r = 0; r < 4; ++r) {
        float tA = fmaf(gsA, accA[mt][r], csA);
        float pA = __builtin_amdgcn_exp2f(__builtin_amdgcn_fmed3f(tA, 0.f, 80.f));
        smA[r] += pA;
        wbA[r] = fmaf(pA, b2f(bvA[r]), wbA[r]);
        float tB = fmaf(gsB, accB[mt][r], csB);
        float pB = __builtin_amdgcn_exp2f(__builtin_amdgcn_fmed3f(tB, 0.f, 80.f));
        smB[r] += pB;
        wbB[r] = fmaf(pB, b2f(bvB[r]), wbB[r]);
      }
    }
    float sA = (smA[0] + smA[1]) + (smA[2] + smA[3]);
    float wA_ = (wbA[0] + wbA[1]) + (wbA[2] + wbA[3]);
    float sB = (smB[0] + smB[1]) + (smB[2] + smB[3]);
    float wB_ = (wbB[0] + wbB[1]) + (wbB[2] + wbB[3]);
    sA += __shfl_xor(sA, 16, 64);  wA_ += __shfl_xor(wA_, 16, 64);
    sB += __shfl_xor(sB, 16, 64);  wB_ += __shfl_xor(wB_, 16, 64);
    sA += __shfl_xor(sA, 32, 64);  wA_ += __shfl_xor(wA_, 32, 64);
    sB += __shfl_xor(sB, 32, 64);  wB_ += __shfl_xor(wB_, 32, 64);
    if (lg == 0) {
      attL[c0] = A[(size_t)n * 256 + c0] - wA_ / sA;
      attL[c1] = A[(size_t)n * 256 + c1] - wB_ / sB;
    }
  }

  // ---- fc (intra-wave, PAIRED o-chains): lane covers c = lane*4..lane*4+3 ----
  {
    float4_t av = *(const float4_t*)&attL[lane * 4];
    #pragma unroll
    for (int op = 0; op < 6; ++op) {
      const int o0 = op * 2, o1 = op * 2 + 1;
      float4_t wv0 = *(const float4_t*)&fcw[(size_t)o0 * 256 + lane * 4];
      float4_t wv1 = *(const float4_t*)&fcw[(size_t)o1 * 256 + lane * 4];
      float s0 = av[0] * wv0[0];
      float s1 = av[0] * wv1[0];
      #pragma unroll
      for (int e = 1; e < 4; ++e) {
        s0 = fmaf(av[e], wv0[e], s0);
        s1 = fmaf(av[e], wv1[e], s1);
      }
      #pragma unroll
      for (int st = 1; st <= 32; st <<= 1) {
        s0 += __shfl_xor(s0, st, 64);
        s1 += __shfl_xor(s1, st, 64);
      }
      if (lane == 0) {
        outp[(size_t)n * 13 + o0] = s0 + fcb[o0];
        outp[(size_t)n * 13 + o1] = s1 + fcb[o1];
      }
    }
    {
      float4_t wv = *(const float4_t*)&fcw[(size_t)12 * 256 + lane * 4];
      float s = av[0] * wv[0];
      s = fmaf(av[1], wv[1], s);
      s = fmaf(av[2], wv[2], s);
      s = fmaf(av[3], wv[3], s);
      #pragma unroll
      for (int st = 1; st <= 32; st <<= 1) s += __shfl_xor(s, st, 64);
      if (lane == 0) outp[(size_t)n * 13 + 12] = s + fcb[12];
    }
  }
}

extern "C" void kernel_launch(void* const* d_in, const int* in_sizes, int n_in,
                              void* d_out, int out_size, void* d_ws, size_t ws_size,
                              hipStream_t stream)
{
  const float* ext = (const float*)d_in[0];
  const float* lab = (const float*)d_in[1];
  const float* w1a = (const float*)d_in[2];
  const float* b1a = (const float*)d_in[3];
  const float* g1a = (const float*)d_in[4];
  const float* be1a= (const float*)d_in[5];
  const float* w1b = (const float*)d_in[6];
  const float* b1b = (const float*)d_in[7];
  const float* g1b = (const float*)d_in[8];
  const float* be1b= (const float*)d_in[9];
  const float* w2a = (const float*)d_in[10];
  const float* b2a = (const float*)d_in[11];
  const float* g2a = (const float*)d_in[12];
  const float* be2a= (const float*)d_in[13];
  const float* w2b = (const float*)d_in[14];
  const float* b2b = (const float*)d_in[15];
  const float* g2b = (const float*)d_in[16];
  const float* be2b= (const float*)d_in[17];
  const float* mw1 = (const float*)d_in[18];
  const float* mb1 = (const float*)d_in[19];
  const float* mg1 = (const float*)d_in[20];
  const float* mbe1= (const float*)d_in[21];
  const float* mw2 = (const float*)d_in[22];
  const float* mb2 = (const float*)d_in[23];
  const float* mg2 = (const float*)d_in[24];
  const float* mbe2= (const float*)d_in[25];
  const float* mw3 = (const float*)d_in[26];
  const float* mb3 = (const float*)d_in[27];
  const float* mg3 = (const float*)d_in[28];
  const float* mbe3= (const float*)d_in[29];
  const float* fcw = (const float*)d_in[30];
  const float* fcb = (const float*)d_in[31];

  char* ws = (char*)d_ws;
  ushort_t* Y1ab = (ushort_t*)(ws);                       // [0,2M) bf16 (dead after enc2)
  float*    PA2  = (float*)(ws);                          // [0,256K) written by proj
  float*    PB2  = (float*)(ws + 262144);                 // [256K,272K)
  float*    Aenc = (float*)(ws + (2u << 20));             // [2M,4M)
  char* b5 = ws + (4u << 20);
  ushort_t* mw2b  = (ushort_t*)(b5);                      // 64x32 bf16
  ushort_t* mw3b  = (ushort_t*)(b5 + 4096);               // 256x64 bf16
  ushort_t* Y1bb  = (ushort_t*)(b5 + 36864);              // 128x512 bf16
  float*    Benc  = (float*)(b5 + 167936);                // 128x256 f32
  ushort_t* BencTb= (ushort_t*)(b5 + 299008);             // 256x128 bf16 (64KB)

  enc_mfma<0, 0, 1><<<dim3(68, 16), 256, 0, stream>>>(
      (const void*)ext, (const void*)w1a, b1a, g1a, be1a, (void*)Y1ab,
      (const void*)lab, (const void*)w2a, b2a, g2a, be2a, (void*)Y1bb,
      (ushort_t*)nullptr, 512, 352, 64);
  enc_mfma<1, 0, 0><<<dim3(68, 8), 256, 0, stream>>>(
      (const void*)Y1ab, (const void*)w1b, b1b, g1b, be1b, (void*)Aenc,
      (const void*)Y1bb, (const void*)w2b, b2b, g2b, be2b, (void*)Benc,
      BencTb, 256, 512, 64);
  proj32<<<553, 256, 0, stream>>>(Aenc, Benc, mw1, mb1, mg1, mbe1, PA2, PB2, 512,
                                  mw2, mw3, mw2b, mw3b);
  main_attn<<<512, 256, 0, stream>>>(PA2, PB2, Aenc, BencTb,
                                     mw2b, mb2, mg2, mbe2, mw3b, mb3, mg3, mbe3,
                                     fcw, fcb, (float*)d_out);
}